// Round 7
// baseline (5366.170 us; speedup 1.0000x reference)
//
#include <hip/hip_runtime.h>
#include <hip/hip_bf16.h>
#include <stdint.h>

// GRU decoder: B=128, IN=256, H=512, SEQ=1024, fp32 out.
// R13 = R12 (incremental sentinel-poll ring, PASSED, 2956us) + three
// scheduling fixes inside the step loop:
//  1) store-shadowed round 1: poll loads issued FIRST, then the deferred
//     reset(slot s+1) + out(h_{s-1}) stores BEHIND them; round-1 wait is
//     vmcnt(8), which (in-order vmcnt) waits exactly {prev publish(4) +
//     polls(16)} and excludes the 8 youngest store acks (ring stores write
//     through to HBM per R12's WRITE_SIZE, so their acks are expensive).
//     Reset causality still holds: step k's vmcnt(8) drains the step-(k-1)
//     reset before pub_k issues; every ring dword has a single writer.
//  2) MFMA-on-arrival: each chunk's 3 MFMAs run the moment it validates,
//     AFTER re-issuing still-invalid chunks -> MFMA hides under re-poll
//     flight, early arrivals consumed during the straggler wait.
//  3) scalarized validation: per-lane ok-bits + shfl_xor AND-reduce +
//     readfirstlane -> scalar branches instead of 16 ballots.
// Ring: depth 8, bf16 pairs, per-dword self-validating (|h|<=1 -> bf16
// bit14==0; sentinel 0xFFFFFFFF), system-scope sc0 sc1 loads / relaxed
// system-scope stores (all R12-proven). No producer drain, no flags.

constexpr int SEQ = 1024;
constexpr int BATCH = 128;
constexpr int IND = 256;
constexpr int HD = 512;
constexpr int BG = 8;
constexpr int HG = 32;
constexpr int ROWS = BATCH / BG;   // 16
constexpr int NT = 3;              // tiles: r, z, n (16 cols each)
constexpr int RING_D = 8;
constexpr int SLOT_DW = BATCH * HD / 2;                      // 32768 dwords
constexpr size_t RING_BYTES = (size_t)RING_D * SLOT_DW * 4;  // 1 MB

using frag16 = __attribute__((ext_vector_type(8))) short;  // 8 bf16
using f32x4  = __attribute__((ext_vector_type(4))) float;
using u32x4  = __attribute__((ext_vector_type(4))) unsigned;

__device__ __forceinline__ float sigmoid_f(float x) {
    return 1.f / (1.f + __expf(-x));
}
__device__ __forceinline__ float tanh_f(float x) {
    float e = __expf(2.f * x);
    return 1.f - 2.f / (e + 1.f);
}
__device__ __forceinline__ short f2bf(float x) {
    return (short)__bfloat16_as_ushort(__float2bfloat16(x));
}

__global__ __launch_bounds__(64, 1) void gru_kernel(
    const float* __restrict__ x,      // [128, 256]
    const float* __restrict__ w_ih,   // [1536, 256]
    const float* __restrict__ w_hh,   // [1536, 512] fp32 (converted here)
    const float* __restrict__ b_ih,   // [1536]
    const float* __restrict__ b_hh,   // [1536]
    unsigned* __restrict__ ring,      // RING_D * [128, 512] bf16, 0xFF-filled
    float* __restrict__ out)          // [128, 1024, 512] fp32
{
    const int lane = threadIdx.x;
    const int bg = blockIdx.x & 7;
    const int hg = blockIdx.x >> 3;
    const int b0 = bg * ROWS;
    const int c0 = hg * 16;
    const int nlo = lane & 15;
    const int quad = lane >> 4;

    int gcol[NT];
    gcol[0] = c0 + nlo;           // r
    gcol[1] = HD + c0 + nlo;      // z
    gcol[2] = 2 * HD + c0 + nlo;  // n

    // ---- stage w_hh slice -> LDS in fragment order (once) ----
    __shared__ frag16 ldsB[NT * 16 * 64];  // 48 KB
#pragma unroll
    for (int t = 0; t < NT; ++t) {
        for (int kc = 0; kc < 16; ++kc) {
            const float* src = w_hh + (size_t)gcol[t] * HD + kc * 32 + quad * 8;
            float4 v0 = *(const float4*)src;
            float4 v1 = *(const float4*)(src + 4);
            frag16 f;
            f[0] = f2bf(v0.x); f[1] = f2bf(v0.y); f[2] = f2bf(v0.z); f[3] = f2bf(v0.w);
            f[4] = f2bf(v1.x); f[5] = f2bf(v1.y); f[6] = f2bf(v1.z); f[7] = f2bf(v1.w);
            ldsB[(t * 16 + kc) * 64 + lane] = f;
        }
    }

    // ---- gi = x @ w_ih.T + b_ih (+ b_hh folded for r,z) ----
    float gi[NT][4];
    float bhn = b_hh[gcol[2]];
#pragma unroll
    for (int t = 0; t < NT; ++t) {
        float bi = b_ih[gcol[t]] + ((t < 2) ? b_hh[gcol[t]] : 0.f);
#pragma unroll
        for (int r = 0; r < 4; ++r) gi[t][r] = bi;
    }
    for (int r = 0; r < 4; ++r) {
        const float4* xr = (const float4*)(x + (size_t)(b0 + quad * 4 + r) * IND);
        for (int kc = 0; kc < IND / 4; ++kc) {
            float4 xv = xr[kc];
#pragma unroll
            for (int t = 0; t < NT; ++t) {
                float4 wv = ((const float4*)(w_ih + (size_t)gcol[t] * IND))[kc];
                gi[t][r] += xv.x * wv.x + xv.y * wv.y + xv.z * wv.z + xv.w * wv.w;
            }
        }
    }

    // ---- recurrence ----
    // A-fragment source: lane reads bf16 row (b0+nlo), cols kc*32+quad*8..+8
    // of ring slot (s-1)%8. Byte offset in slot: row*1024 + kc*64 + quad*16.
    const size_t arow_byte = (size_t)(b0 + nlo) * (HD * 2) + quad * 16;

    float hreg[4] = {0.f, 0.f, 0.f, 0.f};

    for (int s = 0; s < SEQ; ++s) {
        f32x4 C[NT];
#pragma unroll
        for (int t = 0; t < NT; ++t) C[t] = (f32x4){0.f, 0.f, 0.f, 0.f};

        if (s > 0) {
            const char* lrow =
                (const char*)(ring + ((s - 1) & (RING_D - 1)) * SLOT_DW) + arow_byte;
            u32x4 raw[16];
            // issue all 16 polls FIRST
#pragma unroll
            for (int kc = 0; kc < 16; ++kc)
                asm volatile("global_load_dwordx4 %0, %1, off sc0 sc1"
                             : "=&v"(raw[kc]) : "v"(lrow + kc * 64) : "memory");
            // deferred stores (exactly 8 instrs), hidden behind the polls:
            // reset slot s+1 (= (s-1)+2) and out stores of h_{s-1}
            {
                unsigned* rslot = ring + ((s + 1) & (RING_D - 1)) * SLOT_DW;
#pragma unroll
                for (int r = 0; r < 4; ++r) {
                    if ((lane & 1) == 0) {
                        int row = b0 + quad * 4 + r;
                        unsigned idx = (unsigned)(row * HD + (c0 + nlo)) >> 1;
                        __hip_atomic_store(rslot + idx, 0xFFFFFFFFu,
                                           __ATOMIC_RELAXED, __HIP_MEMORY_SCOPE_SYSTEM);
                    }
                }
#pragma unroll
                for (int r = 0; r < 4; ++r) {
                    int row = b0 + quad * 4 + r;
                    __builtin_nontemporal_store(
                        hreg[r],
                        out + (size_t)row * (SEQ * HD) + (size_t)(s - 1) * HD + (c0 + nlo));
                }
            }
            // poll rounds: round 1 waits vmcnt(8) = {pub(4)+polls(16)} done,
            // excluding the 8 store acks just issued (in-order vmcnt).
            unsigned vmask = 0;
            int round = 0;
            do {
                if (round == 0)
                    asm volatile("s_waitcnt vmcnt(8)" ::: "memory");
                else
                    asm volatile("s_waitcnt vmcnt(0)" ::: "memory");
                ++round;
                __builtin_amdgcn_sched_barrier(0);  // validate below the wait
                // per-lane ok bits (valid bf16 pair: bit14 of each half == 0)
                unsigned ok = 0;
#pragma unroll
                for (int kc = 0; kc < 16; ++kc) {
                    if (!(vmask & (1u << kc))) {
                        unsigned orr = raw[kc][0] | raw[kc][1] | raw[kc][2] | raw[kc][3];
                        ok |= ((orr & 0x40004000u) == 0u) ? (1u << kc) : 0u;
                    }
                }
                // cross-lane AND-reduce -> wave-uniform, then to SGPR
#pragma unroll
                for (int d = 1; d < 64; d <<= 1)
                    ok &= (unsigned)__shfl_xor((int)ok, d);
                unsigned newv = __builtin_amdgcn_readfirstlane(ok & ~vmask) & 0xFFFFu;
                unsigned still = 0xFFFFu & ~(vmask | newv);
                // re-issue still-invalid immediately (in flight during MFMA)
#pragma unroll
                for (int kc = 0; kc < 16; ++kc) {
                    if (still & (1u << kc))
                        asm volatile("global_load_dwordx4 %0, %1, off sc0 sc1"
                                     : "=&v"(raw[kc]) : "v"(lrow + kc * 64) : "memory");
                }
                // MFMA newly-valid chunks (hidden under re-poll flight)
#pragma unroll
                for (int kc = 0; kc < 16; ++kc) {
                    if (newv & (1u << kc)) {
                        union { u32x4 u; frag16 f; } cv;
                        cv.u = raw[kc];
#pragma unroll
                        for (int t = 0; t < NT; ++t) {
                            frag16 bfr = ldsB[(t * 16 + kc) * 64 + lane];
                            C[t] = __builtin_amdgcn_mfma_f32_16x16x32_bf16(cv.f, bfr,
                                                                           C[t], 0, 0, 0);
                        }
                    }
                }
                vmask |= newv;
            } while (vmask != 0xFFFFu);
        }

        // gates; publish each hn[r] the moment it's ready
        unsigned* wslot = ring + (s & (RING_D - 1)) * SLOT_DW;
#pragma unroll
        for (int r = 0; r < 4; ++r) {
            float gr  = gi[0][r] + C[0][r];
            float gz  = gi[1][r] + C[1][r];
            float ghn = C[2][r] + bhn;
            float rr = sigmoid_f(gr);
            float zz = sigmoid_f(gz);
            float nn = tanh_f(gi[2][r] + rr * ghn);
            float hn = (1.f - zz) * nn + zz * hreg[r];
            hreg[r] = hn;
            unsigned own = (unsigned)(unsigned short)f2bf(hn);
            unsigned other = (unsigned)__shfl_xor((int)own, 1);
            if ((lane & 1) == 0) {
                int row = b0 + quad * 4 + r;
                unsigned idx = (unsigned)(row * HD + (c0 + nlo)) >> 1;
                __hip_atomic_store(wslot + idx, own | (other << 16),
                                   __ATOMIC_RELAXED, __HIP_MEMORY_SCOPE_SYSTEM);
            }
        }
        // out stores for h_s are deferred into step s+1's poll shadow
    }

    // tail flush: out stores for h_{SEQ-1}
#pragma unroll
    for (int r = 0; r < 4; ++r) {
        int row = b0 + quad * 4 + r;
        __builtin_nontemporal_store(
            hreg[r],
            out + (size_t)row * (SEQ * HD) + (size_t)(SEQ - 1) * HD + (c0 + nlo));
    }
}

extern "C" void kernel_launch(void* const* d_in, const int* in_sizes, int n_in,
                              void* d_out, int out_size, void* d_ws, size_t ws_size,
                              hipStream_t stream) {
    (void)in_sizes; (void)n_in; (void)out_size; (void)ws_size;
    const float* x    = (const float*)d_in[0];
    const float* w_ih = (const float*)d_in[1];
    const float* w_hh = (const float*)d_in[2];
    const float* b_ih = (const float*)d_in[3];
    const float* b_hh = (const float*)d_in[4];

    unsigned* ring = (unsigned*)d_ws;  // proven footprint: 1 MB at offset 0
    hipMemsetAsync(ring, 0xFF, RING_BYTES, stream);  // sentinel fill
    gru_kernel<<<BG * HG, 64, 0, stream>>>(x, w_ih, w_hh, b_ih, b_hh, ring,
                                           (float*)d_out);
}

// Round 9
// 3786.591 us; speedup vs baseline: 1.4172x; 1.4172x over previous
//
#include <hip/hip_runtime.h>
#include <hip/hip_bf16.h>
#include <stdint.h>

// GRU decoder: B=128, IN=256, H=512, SEQ=1024, fp32 out.
// R15 = R12 (incremental sentinel-poll ring, PASSED, 2956us) + paired-wave
// A-sharing. R12's 256 one-wave WGs each poll the IDENTICAL 16KB A-row block
// of their batch group (32x redundant per bg) -> ~1.4TB/s of system-scope
// poll traffic congesting the MALL and inflating the round trip the poll
// waits on (R9->R12 proved poll traffic drives RT). R15 pairs waves: 128 WGs
// x 2 waves; each wave owns 16 output cols (as before) but polls only HALF
// the A chunks (8KB), stages its half to a double-buffered LDS A-buf,
// __syncthreads(), reads the partner's half from LDS. Fabric poll traffic
// halves; exchange cost is ~150ns of LDS/barrier per step.
// ALL sync semantics R12-verbatim per wave: sentinel ring (depth 8, bf16
// pairs, |h|<=1 -> bit14==0, sentinel 0xFFFFFFFF), slot s+2 reset, sc0 sc1
// poll loads, relaxed system-scope publishes, store-inclusive vmcnt(0)
// before validation (R13 lesson: that drain is part of the sync timing),
// ballot validation, monotone incremental re-poll, batched MFMA.
// raw registers split into statically-indexed rown[8]/roth[8] (no dynamic
// ext_vector indexing -> no scratch).

constexpr int SEQ = 1024;
constexpr int BATCH = 128;
constexpr int IND = 256;
constexpr int HD = 512;
constexpr int BG = 8;
constexpr int CG = 16;             // 32-col groups per bg (2 waves x 16 cols)
constexpr int ROWS = BATCH / BG;   // 16
constexpr int NT = 3;              // tiles: r, z, n (16 cols each)
constexpr int RING_D = 8;
constexpr int SLOT_DW = BATCH * HD / 2;                      // 32768 dwords
constexpr size_t RING_BYTES = (size_t)RING_D * SLOT_DW * 4;  // 1 MB

using frag16 = __attribute__((ext_vector_type(8))) short;  // 8 bf16
using f32x4  = __attribute__((ext_vector_type(4))) float;
using u32x4  = __attribute__((ext_vector_type(4))) unsigned;

__device__ __forceinline__ float sigmoid_f(float x) {
    return 1.f / (1.f + __expf(-x));
}
__device__ __forceinline__ float tanh_f(float x) {
    float e = __expf(2.f * x);
    return 1.f - 2.f / (e + 1.f);
}
__device__ __forceinline__ short f2bf(float x) {
    return (short)__bfloat16_as_ushort(__float2bfloat16(x));
}

__global__ __launch_bounds__(128, 1) void gru_kernel(
    const float* __restrict__ x,      // [128, 256]
    const float* __restrict__ w_ih,   // [1536, 256]
    const float* __restrict__ w_hh,   // [1536, 512] fp32 (converted here)
    const float* __restrict__ b_ih,   // [1536]
    const float* __restrict__ b_hh,   // [1536]
    unsigned* __restrict__ ring,      // RING_D * [128, 512] bf16, 0xFF-filled
    float* __restrict__ out)          // [128, 1024, 512] fp32
{
    const int tid  = threadIdx.x;
    const int wv   = tid >> 6;        // 0 or 1
    const int lane = tid & 63;
    const int bg = blockIdx.x & 7;
    const int cg = blockIdx.x >> 3;   // 0..15
    const int b0 = bg * ROWS;
    const int c0 = cg * 32 + wv * 16;
    const int nlo = lane & 15;
    const int quad = lane >> 4;

    int gcol[NT];
    gcol[0] = c0 + nlo;           // r
    gcol[1] = HD + c0 + nlo;      // z
    gcol[2] = 2 * HD + c0 + nlo;  // n

    // ---- LDS: per-wave w_hh fragments (2x48KB) + double-buffered A-buf ----
    __shared__ frag16 ldsB[2][NT * 16 * 64];  // 96 KB
    __shared__ u32x4  abuf[2][16 * 64];       // 32 KB (2 parity buffers)
    frag16* myB = &ldsB[wv][0];

    // ---- stage w_hh slice -> LDS in fragment order (once) ----
#pragma unroll
    for (int t = 0; t < NT; ++t) {
        for (int kc = 0; kc < 16; ++kc) {
            const float* src = w_hh + (size_t)gcol[t] * HD + kc * 32 + quad * 8;
            float4 v0 = *(const float4*)src;
            float4 v1 = *(const float4*)(src + 4);
            frag16 f;
            f[0] = f2bf(v0.x); f[1] = f2bf(v0.y); f[2] = f2bf(v0.z); f[3] = f2bf(v0.w);
            f[4] = f2bf(v1.x); f[5] = f2bf(v1.y); f[6] = f2bf(v1.z); f[7] = f2bf(v1.w);
            myB[(t * 16 + kc) * 64 + lane] = f;
        }
    }

    // ---- gi = x @ w_ih.T + b_ih (+ b_hh folded for r,z) ----
    float gi[NT][4];
    float bhn = b_hh[gcol[2]];
#pragma unroll
    for (int t = 0; t < NT; ++t) {
        float bi = b_ih[gcol[t]] + ((t < 2) ? b_hh[gcol[t]] : 0.f);
#pragma unroll
        for (int r = 0; r < 4; ++r) gi[t][r] = bi;
    }
    for (int r = 0; r < 4; ++r) {
        const float4* xr = (const float4*)(x + (size_t)(b0 + quad * 4 + r) * IND);
        for (int kc = 0; kc < IND / 4; ++kc) {
            float4 xv = xr[kc];
#pragma unroll
            for (int t = 0; t < NT; ++t) {
                float4 wv4 = ((const float4*)(w_ih + (size_t)gcol[t] * IND))[kc];
                gi[t][r] += xv.x * wv4.x + xv.y * wv4.y + xv.z * wv4.z + xv.w * wv4.w;
            }
        }
    }

    // ---- recurrence ----
    // A-fragment source: lane reads bf16 row (b0+nlo), cols kc*32+quad*8..+8
    // of ring slot (s-1)%8. Byte offset in slot: row*1024 + kc*64 + quad*16.
    const size_t arow_byte = (size_t)(b0 + nlo) * (HD * 2) + quad * 16;
    const int kbase = wv * 8;        // own poll half: chunks kbase..kbase+7
    const int obase = 8 - kbase;     // partner half base (wv=0 -> 8, wv=1 -> 0)

    float hreg[4] = {0.f, 0.f, 0.f, 0.f};

    for (int s = 0; s < SEQ; ++s) {
        f32x4 C[NT];
#pragma unroll
        for (int t = 0; t < NT; ++t) C[t] = (f32x4){0.f, 0.f, 0.f, 0.f};

        if (s > 0) {
            const char* lrow =
                (const char*)(ring + ((s - 1) & (RING_D - 1)) * SLOT_DW) + arow_byte;
            u32x4 rown[8];   // own polled half (static indices only)
            u32x4 roth[8];   // partner half via LDS (static indices only)
            // --- poll own 8 chunks; R12-verbatim timing (vmcnt(0) drains the
            //     previous step's publish/reset/out stores before validation)
            unsigned vmask = 0u;
            do {
#pragma unroll
                for (int i = 0; i < 8; ++i) {
                    if (!(vmask & (1u << i))) {
                        asm volatile("global_load_dwordx4 %0, %1, off sc0 sc1"
                                     : "=v"(rown[i])
                                     : "v"(lrow + (kbase + i) * 64) : "memory");
                    }
                }
                asm volatile("s_waitcnt vmcnt(0)" ::: "memory");
                __builtin_amdgcn_sched_barrier(0);  // validate below the wait
#pragma unroll
                for (int i = 0; i < 8; ++i) {
                    if (!(vmask & (1u << i))) {
                        // valid bf16 pair: |h|<=1 -> bit14 of each half == 0
                        unsigned orr = rown[i][0] | rown[i][1] | rown[i][2] | rown[i][3];
                        if (__ballot((orr & 0x40004000u) == 0u) == ~0ull)
                            vmask |= (1u << i);
                    }
                }
            } while (vmask != 0xFFu);
            // --- exchange halves via LDS (double-buffered by step parity)
            u32x4* ab = &abuf[s & 1][0];
#pragma unroll
            for (int i = 0; i < 8; ++i)
                ab[(kbase + i) * 64 + lane] = rown[i];
            __syncthreads();   // partner's half visible after this
#pragma unroll
            for (int i = 0; i < 8; ++i)
                roth[i] = ab[(obase + i) * 64 + lane];
            // --- MFMA all 16 chunks (loaded dwords ARE bf16 A-fragments)
#pragma unroll
            for (int i = 0; i < 8; ++i) {
                union { u32x4 u; frag16 f; } cv;
                cv.u = rown[i];
                const int kc = kbase + i;
#pragma unroll
                for (int t = 0; t < NT; ++t) {
                    frag16 bfr = myB[(t * 16 + kc) * 64 + lane];
                    C[t] = __builtin_amdgcn_mfma_f32_16x16x32_bf16(cv.f, bfr, C[t], 0, 0, 0);
                }
            }
#pragma unroll
            for (int i = 0; i < 8; ++i) {
                union { u32x4 u; frag16 f; } cv;
                cv.u = roth[i];
                const int kc = obase + i;
#pragma unroll
                for (int t = 0; t < NT; ++t) {
                    frag16 bfr = myB[(t * 16 + kc) * 64 + lane];
                    C[t] = __builtin_amdgcn_mfma_f32_16x16x32_bf16(cv.f, bfr, C[t], 0, 0, 0);
                }
            }
        }

        // gates; publish each hn[r] the moment it's ready (R12-verbatim)
        unsigned* wslot = ring + (s & (RING_D - 1)) * SLOT_DW;
        unsigned* rslot = ring + ((s + 2) & (RING_D - 1)) * SLOT_DW;
        float hn[4];
#pragma unroll
        for (int r = 0; r < 4; ++r) {
            float gr  = gi[0][r] + C[0][r];
            float gz  = gi[1][r] + C[1][r];
            float ghn = C[2][r] + bhn;
            float rr = sigmoid_f(gr);
            float zz = sigmoid_f(gz);
            float nn = tanh_f(gi[2][r] + rr * ghn);
            hn[r] = (1.f - zz) * nn + zz * hreg[r];
            hreg[r] = hn[r];
            unsigned own = (unsigned)(unsigned short)f2bf(hn[r]);
            unsigned other = (unsigned)__shfl_xor((int)own, 1);
            if ((lane & 1) == 0) {
                int row = b0 + quad * 4 + r;
                unsigned idx = (unsigned)(row * HD + (c0 + nlo)) >> 1;
                __hip_atomic_store(wslot + idx, own | (other << 16),
                                   __ATOMIC_RELAXED, __HIP_MEMORY_SCOPE_SYSTEM);
            }
        }
        // reset own tile in slot s+2 (sentinel restore; R12-verbatim)
#pragma unroll
        for (int r = 0; r < 4; ++r) {
            if ((lane & 1) == 0) {
                int row = b0 + quad * 4 + r;
                unsigned idx = (unsigned)(row * HD + (c0 + nlo)) >> 1;
                __hip_atomic_store(rslot + idx, 0xFFFFFFFFu,
                                   __ATOMIC_RELAXED, __HIP_MEMORY_SCOPE_SYSTEM);
            }
        }
        // out: non-temporal fp32 stream, don't pollute L2/MALL
#pragma unroll
        for (int r = 0; r < 4; ++r) {
            int row = b0 + quad * 4 + r;
            __builtin_nontemporal_store(
                hn[r], out + (size_t)row * (SEQ * HD) + (size_t)s * HD + (c0 + nlo));
        }
    }
}

extern "C" void kernel_launch(void* const* d_in, const int* in_sizes, int n_in,
                              void* d_out, int out_size, void* d_ws, size_t ws_size,
                              hipStream_t stream) {
    (void)in_sizes; (void)n_in; (void)out_size; (void)ws_size;
    const float* x    = (const float*)d_in[0];
    const float* w_ih = (const float*)d_in[1];
    const float* w_hh = (const float*)d_in[2];
    const float* b_ih = (const float*)d_in[3];
    const float* b_hh = (const float*)d_in[4];

    unsigned* ring = (unsigned*)d_ws;  // proven footprint: 1 MB at offset 0
    hipMemsetAsync(ring, 0xFF, RING_BYTES, stream);  // sentinel fill
    gru_kernel<<<BG * CG, 128, 0, stream>>>(x, w_ih, w_hh, b_ih, b_hh, ring,
                                            (float*)d_out);
}